// Round 5
// baseline (196.197 us; speedup 1.0000x reference)
//
#include <hip/hip_runtime.h>
#include <math.h>

#define EMBED   1024
#define THREEC  3072
#define NH      16
#define HD      64
#define NFEAT   64      // R * M = 2 * 32
#define RN      2
#define MM_     32
#define B_      2
#define T_      4096
#define L_      64      // chunk length
#define NC_     64      // T_ / L_
#define BH_     32      // B_ * NH

typedef __attribute__((ext_vector_type(8))) short bf16x8;
typedef __attribute__((ext_vector_type(4))) float f32x4;

__device__ __forceinline__ float bf2f(short s) {
    unsigned u = ((unsigned)(unsigned short)s) << 16;
    return __builtin_bit_cast(float, u);
}
__device__ __forceinline__ short f2bf(float f) {
    unsigned u = __builtin_bit_cast(unsigned, f);
    u += 0x7fff + ((u >> 16) & 1);
    return (short)(u >> 16);
}
__device__ __forceinline__ void gload16(const short* g, short* l) {
    __builtin_amdgcn_global_load_lds(
        (const __attribute__((address_space(1))) void*)g,
        (__attribute__((address_space(3))) void*)l, 16, 0, 0);
}

// ---------------------------------------------------------------------------
// f32 -> bf16 cast, 8 elems/thread
// ---------------------------------------------------------------------------
__global__ __launch_bounds__(256) void cast_kernel(
    const float* __restrict__ in, short* __restrict__ out, int n8)
{
    int i = blockIdx.x * 256 + threadIdx.x;
    if (i >= n8) return;
    const float4* p = (const float4*)in + (size_t)i * 2;
    float4 a = p[0], b = p[1];
    bf16x8 o = { f2bf(a.x), f2bf(a.y), f2bf(a.z), f2bf(a.w),
                 f2bf(b.x), f2bf(b.y), f2bf(b.z), f2bf(b.w) };
    *((bf16x8*)out + i) = o;
}

// ---------------------------------------------------------------------------
// omega [R,H,D,M] fp32 -> omgT[h][f=r*32+m][d] bf16 hi/lo split
// ---------------------------------------------------------------------------
__global__ __launch_bounds__(256) void omega_prep(
    const float* __restrict__ omega, short* __restrict__ hi, short* __restrict__ lo)
{
    int i = blockIdx.x * 256 + threadIdx.x;   // over H*F*D = 65536
    if (i >= NH * NFEAT * HD) return;
    int d = i & 63;
    int f = (i >> 6) & 63;
    int h = i >> 12;
    int r = f >> 5, m = f & 31;
    float w = omega[(((size_t)(r * NH + h) * HD + d) * MM_) + m];
    short a = f2bf(w);
    hi[i] = a;
    lo[i] = f2bf(w - bf2f(a));
}

// ---------------------------------------------------------------------------
// Pipelined 256x256 bf16 MFMA GEMM. BK=32, 4 LDS buffers, 512 threads
// (8 waves, 2x4; each wave outputs 128x64). Counted-vmcnt pipeline:
//   compute kt (regs) || ds-read kt+1 frags || stage kt+3 (global_load_lds).
// LDS granule swizzle g^=row&3 on both staging source and ds_read address.
// C[m,n] = sum_k A[m*K+k]*W[n*K+k] + bias[n], bf16 out.
// Requires M%256==0, N%256==0, K%64==0, K>=192.
// ---------------------------------------------------------------------------
__device__ __forceinline__ bf16x8 lds_frag(const short* base, int row, int G) {
    const int off = row * 32 + ((G ^ (row & 3)) << 3);
    return *(const bf16x8*)(base + off);
}

__global__ __launch_bounds__(512, 2) void gemm_pipe256(
    const short* __restrict__ A,      // [M][K] bf16
    const short* __restrict__ W,      // [N][K] bf16
    const float* __restrict__ bias,   // [N]
    short* __restrict__ Cb,           // [M][N] bf16
    int M, int N, int K)
{
    __shared__ short lA[4][256 * 32];
    __shared__ short lB[4][256 * 32];

    const int tid  = threadIdx.x;
    const int nbn  = N >> 8;
    // XCD-aware swizzle (grid must be divisible by 8; 384 is)
    const int nwg  = gridDim.x;
    const int cpx  = nwg >> 3;
    const int bid  = blockIdx.x;
    const int swz  = (bid & 7) * cpx + (bid >> 3);
    const int bm   = (swz / nbn) << 8;
    const int bn   = (swz % nbn) << 8;

    const int lane = tid & 63;
    const int wid  = tid >> 6;
    const int wm   = wid >> 2;        // 0..1
    const int wn   = wid & 3;         // 0..3
    const int lr   = lane & 15;
    const int G    = lane >> 4;       // k-granule 0..3

    const int r2   = tid >> 2;        // 0..127 staging row
    const int gs   = (tid & 3) ^ (r2 & 3);   // pre-swizzled source granule
    const int KT   = K >> 5;

    auto stageA = [&](int buf, int kt) {
        const int k0 = kt << 5;
        gload16(&A[(size_t)(bm + r2) * K + k0 + gs * 8],       &lA[buf][tid * 8]);
        gload16(&A[(size_t)(bm + 128 + r2) * K + k0 + gs * 8], &lA[buf][4096 + tid * 8]);
    };
    auto stageB = [&](int buf, int kt) {
        const int k0 = kt << 5;
        gload16(&W[(size_t)(bn + r2) * K + k0 + gs * 8],       &lB[buf][tid * 8]);
        gload16(&W[(size_t)(bn + 128 + r2) * K + k0 + gs * 8], &lB[buf][4096 + tid * 8]);
    };

    f32x4 acc[8][4] = {};
    bf16x8 ra0[8], rb0[4], ra1[8], rb1[4];

#define DS_READ_A(dst, bufidx, frlo)                                          \
    _Pragma("unroll")                                                         \
    for (int fr = (frlo); fr < (frlo) + 4; ++fr)                              \
        dst[fr] = lds_frag(&lA[bufidx][0], wm * 128 + fr * 16 + lr, G);
#define DS_READ_B(dst, bufidx, fclo)                                          \
    _Pragma("unroll")                                                         \
    for (int fc = (fclo); fc < (fclo) + 2; ++fc)                              \
        dst[fc] = lds_frag(&lB[bufidx][0], wn * 64 + fc * 16 + lr, G);
#define MFMA_HALF(RA, RB, frlo)                                               \
    _Pragma("unroll")                                                         \
    for (int fr = (frlo); fr < (frlo) + 4; ++fr)                              \
        _Pragma("unroll")                                                     \
        for (int fc = 0; fc < 4; ++fc)                                        \
            acc[fr][fc] = __builtin_amdgcn_mfma_f32_16x16x32_bf16(            \
                RA[fr], RB[fc], acc[fr][fc], 0, 0, 0);

#define KTILE_BODY(kt, RA_CUR, RB_CUR, RA_NXT, RB_NXT)                        \
    {                                                                         \
        const int bstg = ((kt) + 3) & 3;                                      \
        const int bnxt = ((kt) + 1) & 3;                                      \
        if ((kt) + 2 < KT) asm volatile("s_waitcnt vmcnt(4)" ::: "memory");   \
        else               asm volatile("s_waitcnt vmcnt(0)" ::: "memory");   \
        __builtin_amdgcn_s_barrier();                                         \
        __builtin_amdgcn_sched_barrier(0);                                    \
        if ((kt) + 1 < KT) { DS_READ_A(RA_NXT, bnxt, 0)                       \
                             DS_READ_B(RB_NXT, bnxt, 0) }                     \
        if ((kt) + 3 < KT) stageA(bstg, (kt) + 3);                            \
        __builtin_amdgcn_s_setprio(1);                                        \
        MFMA_HALF(RA_CUR, RB_CUR, 0)                                          \
        __builtin_amdgcn_s_setprio(0);                                        \
        __builtin_amdgcn_sched_barrier(0);                                    \
        if ((kt) + 1 < KT) { DS_READ_A(RA_NXT, bnxt, 4)                       \
                             DS_READ_B(RB_NXT, bnxt, 2) }                     \
        if ((kt) + 3 < KT) stageB(bstg, (kt) + 3);                            \
        __builtin_amdgcn_s_setprio(1);                                        \
        MFMA_HALF(RA_CUR, RB_CUR, 4)                                          \
        __builtin_amdgcn_s_setprio(0);                                        \
        __builtin_amdgcn_sched_barrier(0);                                    \
    }

    // prologue: stage K-tiles 0,1,2 (buffers 0,1,2)
    stageA(0, 0); stageB(0, 0);
    stageA(1, 1); stageB(1, 1);
    stageA(2, 2); stageB(2, 2);
    asm volatile("s_waitcnt vmcnt(8)" ::: "memory");
    __builtin_amdgcn_s_barrier();
    __builtin_amdgcn_sched_barrier(0);
    DS_READ_A(ra0, 0, 0) DS_READ_A(ra0, 0, 4)
    DS_READ_B(rb0, 0, 0) DS_READ_B(rb0, 0, 2)

    const int KT2 = KT >> 1;
    for (int kti = 0; kti < KT2; ++kti) {
        const int kt = kti * 2;
        KTILE_BODY(kt,     ra0, rb0, ra1, rb1)
        KTILE_BODY(kt + 1, ra1, rb1, ra0, rb0)
    }
#undef DS_READ_A
#undef DS_READ_B
#undef MFMA_HALF
#undef KTILE_BODY

    // epilogue: C/D layout col = lane&15, row = (lane>>4)*4 + j
    #pragma unroll
    for (int fc = 0; fc < 4; ++fc) {
        const int col = bn + wn * 64 + fc * 16 + lr;
        const float bv = bias[col];
        #pragma unroll
        for (int fr = 0; fr < 8; ++fr) {
            const int rbase = bm + wm * 128 + fr * 16 + G * 4;
            #pragma unroll
            for (int j = 0; j < 4; ++j)
                Cb[(size_t)(rbase + j) * N + col] = f2bf(acc[fr][fc][j] + bv);
        }
    }
}

// ---------------------------------------------------------------------------
// bf16 MFMA GEMM (m97 structure) — used for the output projection
// ---------------------------------------------------------------------------
template<int OUTBF>
__global__ __launch_bounds__(256) void gemm_bf16(
    const short* __restrict__ A,      // [M][K] bf16
    const short* __restrict__ W,      // [N][K] bf16
    const float* __restrict__ bias,   // [N]
    float* __restrict__ Cf, short* __restrict__ Cb,
    int M, int N, int K)
{
    __shared__ short lA[2][128 * 32];
    __shared__ short lB[2][128 * 32];
    const int tid  = threadIdx.x;
    const int bm   = blockIdx.y * 128;
    const int bn   = blockIdx.x * 128;
    const int lane = tid & 63;
    const int wave = tid >> 6;
    const int row0 = (wave >> 1) * 64;
    const int col0 = (wave & 1) * 64;
    const int lr   = lane & 15;
    const int kg8  = (lane >> 4) * 8;

    f32x4 acc[4][4] = {};

#define STAGE(buf, k0)                                                        \
    {                                                                         \
        _Pragma("unroll")                                                     \
        for (int i = 0; i < 2; ++i) {                                         \
            int idx = i * 256 + tid;                                          \
            int row = idx >> 2, kq = (idx & 3) * 8;                           \
            gload16(&A[(size_t)(bm + row) * K + (k0) + kq], &lA[buf][idx * 8]); \
            gload16(&W[(size_t)(bn + row) * K + (k0) + kq], &lB[buf][idx * 8]); \
        }                                                                     \
    }

    const int KT = K >> 5;
    STAGE(0, 0);
    __syncthreads();
    int cur = 0;
    for (int kt = 0; kt < KT; ++kt) {
        if (kt + 1 < KT) STAGE(cur ^ 1, (kt + 1) * 32);
        const short* As = lA[cur];
        const short* Bs = lB[cur];
        bf16x8 af[4], bfr[4];
        #pragma unroll
        for (int m = 0; m < 4; ++m)
            af[m] = *(const bf16x8*)&As[(row0 + m * 16 + lr) * 32 + kg8];
        #pragma unroll
        for (int n = 0; n < 4; ++n)
            bfr[n] = *(const bf16x8*)&Bs[(col0 + n * 16 + lr) * 32 + kg8];
        #pragma unroll
        for (int m = 0; m < 4; ++m)
            #pragma unroll
            for (int n = 0; n < 4; ++n)
                acc[m][n] = __builtin_amdgcn_mfma_f32_16x16x32_bf16(
                    af[m], bfr[n], acc[m][n], 0, 0, 0);
        __syncthreads();
        cur ^= 1;
    }
#undef STAGE

    #pragma unroll
    for (int n = 0; n < 4; ++n) {
        const int col = bn + col0 + n * 16 + (lane & 15);
        const float bv = bias[col];
        #pragma unroll
        for (int m = 0; m < 4; ++m) {
            const int rbase = bm + row0 + m * 16 + (lane >> 4) * 4;
            #pragma unroll
            for (int j = 0; j < 4; ++j) {
                const float v = acc[m][n][j] + bv;
                if (OUTBF) Cb[(size_t)(rbase + j) * N + col] = f2bf(v);
                else       Cf[(size_t)(rbase + j) * N + col] = v;
            }
        }
    }
}

// ---------------------------------------------------------------------------
// Feature map (MFMA), writing bf16 qf/kf.
// ---------------------------------------------------------------------------
__global__ __launch_bounds__(256) void features_mfma(
    const short* __restrict__ qkvb,       // [B, T, 3C] bf16
    const short* __restrict__ omgH,       // [H][64f][64d] bf16 (hi)
    const short* __restrict__ omgL,       // [H][64f][64d] bf16 (lo)
    const float* __restrict__ qn,
    const float* __restrict__ qw,
    short* __restrict__ qf,               // [BH, T, 64] bf16
    short* __restrict__ kf)
{
    __shared__ short zq[64][72];
    __shared__ short zk[64][72];
    __shared__ short omh[64][72];
    __shared__ short oml[64][72];
    __shared__ float invn[2][64];

    const int tid = threadIdx.x;
    const int bh  = blockIdx.x >> 6;      // 0..31
    const int tb  = blockIdx.x & 63;      // 0..63
    const int b   = bh >> 4, h = bh & 15;
    const int t0  = tb * 64;

    {
        const int row = tid >> 2;
        const int c0  = (tid & 3) * 16;
        const size_t zbase = ((size_t)(b * T_ + t0 + row)) * THREEC + h * HD + c0;
        const size_t obase = ((size_t)h * NFEAT + row) * HD + c0;
        *(bf16x8*)&zq[row][c0]      = *(const bf16x8*)&qkvb[zbase];
        *(bf16x8*)&zq[row][c0 + 8]  = *(const bf16x8*)&qkvb[zbase + 8];
        *(bf16x8*)&zk[row][c0]      = *(const bf16x8*)&qkvb[zbase + EMBED];
        *(bf16x8*)&zk[row][c0 + 8]  = *(const bf16x8*)&qkvb[zbase + EMBED + 8];
        *(bf16x8*)&omh[row][c0]     = *(const bf16x8*)&omgH[obase];
        *(bf16x8*)&omh[row][c0 + 8] = *(const bf16x8*)&omgH[obase + 8];
        *(bf16x8*)&oml[row][c0]     = *(const bf16x8*)&omgL[obase];
        *(bf16x8*)&oml[row][c0 + 8] = *(const bf16x8*)&omgL[obase + 8];
    }
    __syncthreads();

    {
        const int t = tid >> 2;
        const int q = tid & 3;
        #pragma unroll
        for (int p = 0; p < 2; ++p) {
            const short* Z = p ? &zk[t][q * 16] : &zq[t][q * 16];
            float ss = 0.0f;
            #pragma unroll
            for (int j = 0; j < 16; ++j) { float v = bf2f(Z[j]); ss += v * v; }
            ss += __shfl_xor(ss, 1, 64);
            ss += __shfl_xor(ss, 2, 64);
            if (q == 0) invn[p][t] = 1.0f / fmaxf(sqrtf(ss), 1e-12f);
        }
    }
    __syncthreads();

    const int wave = tid >> 6;
    const int lane = tid & 63;
    const int p    = wave >> 1;           // 0 = q, 1 = k
    const int half = wave & 1;            // token half
    const short (*Z)[72] = p ? zk : zq;

    const float s0 = qn[0], s1 = qn[1];
    const float sq2s0 = sqrtf(2.0f * fmaxf(s0, 0.0f));
    const float sq2s1 = sqrtf(2.0f * fmaxf(s1, 0.0f));
    const float sc0 = sqrtf(fmaxf(qw[0], 0.0f)) * (1.0f / 32.0f);
    const float sc1 = sqrtf(fmaxf(qw[1], 0.0f)) * (1.0f / 32.0f);

    const int lr  = lane & 15;
    const int kg8 = (lane >> 4) * 8;

    f32x4 acc[2][4] = {};
    #pragma unroll
    for (int kk = 0; kk < 2; ++kk) {
        bf16x8 a[2], bh8[4], bl8[4];
        #pragma unroll
        for (int m = 0; m < 2; ++m)
            a[m] = *(const bf16x8*)&Z[half * 32 + m * 16 + lr][kk * 32 + kg8];
        #pragma unroll
        for (int n = 0; n < 4; ++n) {
            bh8[n] = *(const bf16x8*)&omh[n * 16 + lr][kk * 32 + kg8];
            bl8[n] = *(const bf16x8*)&oml[n * 16 + lr][kk * 32 + kg8];
        }
        #pragma unroll
        for (int m = 0; m < 2; ++m)
            #pragma unroll
            for (int n = 0; n < 4; ++n) {
                acc[m][n] = __builtin_amdgcn_mfma_f32_16x16x32_bf16(
                    a[m], bh8[n], acc[m][n], 0, 0, 0);
                acc[m][n] = __builtin_amdgcn_mfma_f32_16x16x32_bf16(
                    a[m], bl8[n], acc[m][n], 0, 0, 0);
            }
    }

    short* dstbase = (p ? kf : qf) + ((size_t)bh * T_ + t0) * NFEAT;
    #pragma unroll
    for (int n = 0; n < 4; ++n) {
        const int f = n * 16 + (lane & 15);
        const float s_r   = (n < 2) ? s0 : s1;
        const float sq2s  = (n < 2) ? sq2s0 : sq2s1;
        const float scale = (n < 2) ? sc0 : sc1;
        #pragma unroll
        for (int m = 0; m < 2; ++m) {
            const int tb4 = half * 32 + m * 16 + (lane >> 4) * 4;
            #pragma unroll
            for (int j = 0; j < 4; ++j) {
                const int t = tb4 + j;
                const float proj = acc[m][n][j] * invn[p][t];
                const float arg = fminf(fmaxf(proj * sq2s - s_r, -20.0f), 20.0f);
                const float val = proj * proj * __expf(arg) * scale;
                dstbase[(size_t)t * NFEAT + f] = f2bf(val);
            }
        }
    }
}

// ---------------------------------------------------------------------------
// Per-chunk KV sums. Writes cKV TRANSPOSED: [chunk][d][f] = S[f][d].
// ---------------------------------------------------------------------------
__global__ __launch_bounds__(256) void chunk_sums(
    const short* __restrict__ kf,         // bf16
    const short* __restrict__ qkvb,
    float* __restrict__ cKV,              // [BH*NC, 64d, 64f]
    float* __restrict__ cK)               // [BH*NC, 64]
{
    __shared__ float kfs[64][64];
    __shared__ float vs[64][64];
    float (*st)[65] = (float(*)[65])kfs;  // reuse after compute

    const int tid = threadIdx.x;
    const int chunk = blockIdx.x;
    const int bh = chunk >> 6, c = chunk & 63;
    const int b = bh >> 4, h = bh & 15;
    const int t0 = c * L_;

    {
        const int row = tid >> 2;
        const int c0  = (tid & 3) * 16;
        const short* krow = kf + ((size_t)bh * T_ + t0 + row) * NFEAT;
        const short* vrow = qkvb + ((size_t)(b * T_ + t0 + row)) * THREEC + 2 * EMBED + h * HD;
        bf16x8 k0 = *(const bf16x8*)&krow[c0], k1 = *(const bf16x8*)&krow[c0 + 8];
        bf16x8 v0 = *(const bf16x8*)&vrow[c0], v1 = *(const bf16x8*)&vrow[c0 + 8];
        #pragma unroll
        for (int j = 0; j < 8; ++j) {
            kfs[row][c0 + j]     = bf2f(k0[j]);
            kfs[row][c0 + 8 + j] = bf2f(k1[j]);
            vs[row][c0 + j]      = bf2f(v0[j]);
            vs[row][c0 + 8 + j]  = bf2f(v1[j]);
        }
    }
    __syncthreads();

    const int f  = tid >> 2;
    const int d0 = (tid & 3) * 16;
    float acc[16] = {};
    float ks = 0.0f;
    for (int t = 0; t < L_; ++t) {
        const float kft = kfs[t][f];
        ks += kft;
        #pragma unroll
        for (int j = 0; j < 16; ++j) acc[j] += kft * vs[t][d0 + j];
    }
    if ((tid & 3) == 0) cK[(size_t)chunk * NFEAT + f] = ks;
    __syncthreads();   // done reading kfs/vs

    #pragma unroll
    for (int j = 0; j < 16; ++j) st[f][d0 + j] = acc[j];
    __syncthreads();

    {
        const int d  = tid >> 2;
        const int f0 = (tid & 3) * 16;
        float* dst = cKV + (size_t)chunk * (NFEAT * HD) + tid * 16;
        #pragma unroll
        for (int q = 0; q < 4; ++q) {
            float4 o;
            o.x = st[f0 + q * 4 + 0][d];
            o.y = st[f0 + q * 4 + 1][d];
            o.z = st[f0 + q * 4 + 2][d];
            o.w = st[f0 + q * 4 + 3][d];
            *(float4*)&dst[q * 4] = o;
        }
    }
}

// ---------------------------------------------------------------------------
// Exclusive prefix over chunks. grid: BH_*4 blocks; depth-2 prefetch.
// ---------------------------------------------------------------------------
__global__ __launch_bounds__(256) void prefix_scan(
    float* __restrict__ cKV, float* __restrict__ cK)
{
    const int bh  = blockIdx.x >> 2;
    const int sl  = blockIdx.x & 3;
    const int tid = threadIdx.x;
    float4* base = (float4*)(cKV + (size_t)bh * NC_ * (NFEAT * HD) + sl * 1024) + tid;
    float4 n0 = base[0];
    float4 n1 = base[1024];
    float4 pref; pref.x = pref.y = pref.z = pref.w = 0.0f;
    for (int c = 0; c < NC_; ++c) {
        float4 cur = n0;
        n0 = n1;
        if (c + 2 < NC_) n1 = base[(size_t)(c + 2) * 1024];
        else { n1.x = n1.y = n1.z = n1.w = 0.0f; }
        base[(size_t)c * 1024] = pref;
        pref.x += cur.x; pref.y += cur.y; pref.z += cur.z; pref.w += cur.w;
    }
    if (sl == 0 && tid < 64) {
        float* kb = cK + (size_t)bh * NC_ * NFEAT + tid;
        float m0 = kb[0];
        float m1 = kb[64];
        float p = 0.0f;
        for (int c = 0; c < NC_; ++c) {
            float cu = m0;
            m0 = m1;
            m1 = (c + 2 < NC_) ? kb[(size_t)(c + 2) * 64] : 0.0f;
            kb[(size_t)c * 64] = p;
            p += cu;
        }
    }
}

// ---------------------------------------------------------------------------
// Intra-chunk causal attention via MFMA. 4 waves, each owns a 16-row band.
// ---------------------------------------------------------------------------
__global__ __launch_bounds__(256) void intra_mfma(
    const short* __restrict__ qf,         // [BH,T,64] bf16
    const short* __restrict__ kf,
    const short* __restrict__ qkvb,       // v region (bf16)
    const float* __restrict__ cKV,        // [chunk][d][f] prefix fp32
    const float* __restrict__ cK,         // [chunk][f] prefix fp32
    short* __restrict__ attnb)            // [B*T, EMBED] bf16
{
    __shared__ short Qs[64][72];
    __shared__ short Ks[64][72];
    __shared__ short Vt[64][72];          // V^T: [d][t]
    __shared__ short Pp[64][72];          // KVp^T: [d][f]
    __shared__ short At[64][72];          // masked A: [t][s]
    __shared__ float rs_l[64], qkp_l[64], cKp[64];

    const int tid = threadIdx.x;
    const int chunk = blockIdx.x;
    const int bh = chunk >> 6, c = chunk & 63;
    const int b = bh >> 4, h = bh & 15;
    const int t0 = c * L_;

    {
        const int row = tid >> 2;
        const int c0  = (tid & 3) * 16;
        const short* qrow = qf + ((size_t)bh * T_ + t0 + row) * NFEAT;
        const short* krow = kf + ((size_t)bh * T_ + t0 + row) * NFEAT;
        const short* vrow = qkvb + ((size_t)(b * T_ + t0 + row)) * THREEC + 2 * EMBED + h * HD;
        *(bf16x8*)&Qs[row][c0]     = *(const bf16x8*)&qrow[c0];
        *(bf16x8*)&Qs[row][c0 + 8] = *(const bf16x8*)&qrow[c0 + 8];
        *(bf16x8*)&Ks[row][c0]     = *(const bf16x8*)&krow[c0];
        *(bf16x8*)&Ks[row][c0 + 8] = *(const bf16x8*)&krow[c0 + 8];
        bf16x8 v0 = *(const bf16x8*)&vrow[c0], v1 = *(const bf16x8*)&vrow[c0 + 8];
        #pragma unroll
        for (int j = 0; j < 8; ++j) {
            Vt[c0 + j][row]     = v0[j];
            Vt[c0 + 8 + j][row] = v1[j];
        }
        const float* pbase = cKV + (size_t)chunk * (NFEAT * HD) + tid * 16;
        float4 p0 = *(const float4*)&pbase[0],  p1 = *(const float4*)&pbase[4];
        float4 p2 = *(const float4*)&pbase[8],  p3 = *(const float4*)&pbase[12];
        bf16x8 o0 = { f2bf(p0.x), f2bf(p0.y), f2bf(p0.z), f2bf(p0.w),
                      f2bf(p1.x), f2bf(p1.y), f2bf(p1.z), f2bf(p1.w) };
        bf16x8 o1 = { f2bf(p2.x), f2bf(p2.y), f2bf(p2.z), f2bf(p2.w),
                      f2bf(p3.x), f2bf(p3.y), f2bf(p3.z), f2bf(p3.w) };
        *(bf16x8*)&Pp[row][c0]     = o0;
        *(bf16x8*)&Pp[row][c0 + 8] = o1;
        if (tid < 64) cKp[tid] = cK[(size_t)chunk * NFEAT + tid];
    }
    __syncthreads();

    const int wave = tid >> 6;
    const int lane = tid & 63;
    const int lr   = lane & 15;
    const int kg   = (lane >> 4) * 8;
    const int r0   = wave * 16;

    bf16x8 aq[2];
    aq[0] = *(const bf16x8*)&Qs[r0 + lr][kg];
    aq[1] = *(const bf16x8*)&Qs[r0 + lr][32 + kg];
    f32x4 accA[4] = {};
    #pragma unroll
    for (int n = 0; n < 4; ++n) {
        accA[n] = __builtin_amdgcn_mfma_f32_16x16x32_bf16(
            aq[0], *(const bf16x8*)&Ks[n * 16 + lr][kg], accA[n], 0, 0, 0);
        accA[n] = __builtin_amdgcn_mfma_f32_16x16x32_bf16(
            aq[1], *(const bf16x8*)&Ks[n * 16 + lr][32 + kg], accA[n], 0, 0, 0);
    }
    float rsum[4] = {0.0f, 0.0f, 0.0f, 0.0f};
    #pragma unroll
    for (int n = 0; n < 4; ++n) {
        const int s = n * 16 + lr;
        #pragma unroll
        for (int j = 0; j < 4; ++j) {
            const int t = r0 + (lane >> 4) * 4 + j;
            const float a = (s <= t) ? accA[n][j] : 0.0f;
            rsum[j] += a;
            At[t][s] = f2bf(a);
        }
    }
    #pragma unroll
    for (int j = 0; j < 4; ++j) {
        rsum[j] += __shfl_xor(rsum[j], 1, 64);
        rsum[j] += __shfl_xor(rsum[j], 2, 64);
        rsum[j] += __shfl_xor(rsum[j], 4, 64);
        rsum[j] += __shfl_xor(rsum[j], 8, 64);
    }
    if (lr == 0) {
        #pragma unroll
        for (int j = 0; j < 4; ++j) rs_l[r0 + (lane >> 4) * 4 + j] = rsum[j];
    }

    {
        const int t  = tid >> 2;
        const int fq = (tid & 3) * 16;
        float s = 0.0f;
        #pragma unroll
        for (int j = 0; j < 16; ++j) s += bf2f(Qs[t][fq + j]) * cKp[fq + j];
        s += __shfl_xor(s, 1, 64);
        s += __shfl_xor(s, 2, 64);
        if ((tid & 3) == 0) qkp_l[t] = s;
    }
    __syncthreads();

    bf16x8 aa[2];
    aa[0] = *(const bf16x8*)&At[r0 + lr][kg];
    aa[1] = *(const bf16x8*)&At[r0 + lr][32 + kg];
    f32x4 acc[4] = {};
    #pragma unroll
    for (int n = 0; n < 4; ++n) {
        acc[n] = __builtin_amdgcn_mfma_f32_16x16x32_bf16(
            aa[0], *(const bf16x8*)&Vt[n * 16 + lr][kg], acc[n], 0, 0, 0);
        acc[n] = __builtin_amdgcn_mfma_f32_16x16x32_bf16(
            aa[1], *(const bf16x8*)&Vt[n * 16 + lr][32 + kg], acc[n], 0, 0, 0);
        acc[n] = __builtin_amdgcn_mfma_f32_16x16x32_bf16(
            aq[0], *(const bf16x8*)&Pp[n * 16 + lr][kg], acc[n], 0, 0, 0);
        acc[n] = __builtin_amdgcn_mfma_f32_16x16x32_bf16(
            aq[1], *(const bf16x8*)&Pp[n * 16 + lr][32 + kg], acc[n], 0, 0, 0);
    }

    float inv[4];
    #pragma unroll
    for (int j = 0; j < 4; ++j) {
        const int t = r0 + (lane >> 4) * 4 + j;
        inv[j] = 1.0f / fmaxf(rs_l[t] + qkp_l[t], 1e-6f);
    }
    #pragma unroll
    for (int n = 0; n < 4; ++n) {
        const int d = n * 16 + lr;
        #pragma unroll
        for (int j = 0; j < 4; ++j) {
            const int t = r0 + (lane >> 4) * 4 + j;
            attnb[((size_t)(b * T_ + t0 + t)) * EMBED + h * HD + d] =
                f2bf(acc[n][j] * inv[j]);
        }
    }
}

// ---------------------------------------------------------------------------
extern "C" void kernel_launch(void* const* d_in, const int* in_sizes, int n_in,
                              void* d_out, int out_size, void* d_ws, size_t ws_size,
                              hipStream_t stream)
{
    const float* x     = (const float*)d_in[0];
    const float* w_qkv = (const float*)d_in[1];
    const float* b_qkv = (const float*)d_in[2];
    const float* w_out = (const float*)d_in[3];
    const float* b_out = (const float*)d_in[4];
    const float* omega = (const float*)d_in[5];
    const float* qn    = (const float*)d_in[6];
    const float* qw    = (const float*)d_in[7];
    float* out = (float*)d_out;

    // workspace layout (shorts first, then floats)
    short* xb    = (short*)d_ws;               //  8,388,608
    short* wqb   = xb    + 8388608;            //  3,145,728
    short* wob   = wqb   + 3145728;            //  1,048,576
    short* qkvb  = wob   + 1048576;            // 25,165,824
    short* attnb = qkvb  + 25165824;           //  8,388,608
    short* omgH  = attnb + 8388608;            //     65,536
    short* omgL  = omgH  + 65536;              //     65,536
    short* qfb   = omgL  + 65536;              //  8,388,608
    short* kfb   = qfb   + 8388608;            //  8,388,608
    float* cKV   = (float*)(kfb + 8388608);    //  8,388,608 floats
    float* cK    = cKV + 8388608;              //    131,072 floats

    const int M = B_ * T_;   // 8192

    cast_kernel<<<dim3(8388608 / 8 / 256), 256, 0, stream>>>(x, xb, 8388608 / 8);
    cast_kernel<<<dim3(3145728 / 8 / 256), 256, 0, stream>>>(w_qkv, wqb, 3145728 / 8);
    cast_kernel<<<dim3(1048576 / 8 / 256), 256, 0, stream>>>(w_out, wob, 1048576 / 8);
    omega_prep<<<dim3(256), 256, 0, stream>>>(omega, omgH, omgL);

    // 1. qkv = x @ w_qkv^T + b_qkv  (bf16 out) — pipelined 256^2 kernel
    gemm_pipe256<<<dim3((M / 256) * (THREEC / 256)), 512, 0, stream>>>(
        xb, wqb, b_qkv, qkvb, M, THREEC, EMBED);
    // 2. features (MFMA, bf16 out)
    features_mfma<<<dim3(BH_ * (T_ / 64)), 256, 0, stream>>>(
        qkvb, omgH, omgL, qn, qw, qfb, kfb);
    // 3. per-chunk KV sums (transposed cKV)
    chunk_sums<<<dim3(BH_ * NC_), 256, 0, stream>>>(kfb, qkvb, cKV, cK);
    // 4. exclusive prefix over chunks
    prefix_scan<<<dim3(BH_ * 4), 256, 0, stream>>>(cKV, cK);
    // 5. intra-chunk attention (MFMA) -> bf16 attn [B*T, C]
    intra_mfma<<<dim3(BH_ * NC_), 256, 0, stream>>>(qfb, kfb, qkvb, cKV, cK, attnb);
    // 6. out = attn @ w_out^T + b_out (fp32 out)
    gemm_bf16<0><<<dim3(EMBED / 128, M / 128), 256, 0, stream>>>(
        attnb, wob, b_out, out, nullptr, M, EMBED, EMBED);
}